// Round 5
// baseline (1177.968 us; speedup 1.0000x reference)
//
#include <hip/hip_runtime.h>
#include <hip/hip_bf16.h>
#include <cmath>

#define NL 16
#define TSIZE (1u << 19)
#define TMASK (TSIZE - 1u)

typedef __attribute__((ext_vector_type(8))) short bf16x8;     // 8 bf16 (4 VGPRs)
typedef __attribute__((ext_vector_type(4))) float f32x4;

struct LevelParams {
  float scale[NL];
  unsigned res[NL];
  unsigned dense_mask;
};

static __device__ __forceinline__ short f2bf(float f) {
  __hip_bfloat16 h = __float2bfloat16(f);
  return *reinterpret_cast<short*>(&h);
}
static __device__ __forceinline__ short lo16(unsigned u) { return (short)(u & 0xffffu); }
static __device__ __forceinline__ short hi16(unsigned u) { return (short)(u >> 16); }

// ============ Kernel 1: encode. 2 rays x 2 levels per thread, XCD-pinned. ===
// blockIdx%8 -> XCD (empirical round-robin); levels (k, k+8) pinned to XCD k
// => per-XCD L2 working set 4-8 MB (round-4: FETCH 6.0->1.5 GB, verified).
// 32 gathers in flight per thread attacks the latency*parallelism bound
// (round-4 model: 0.48 gathers/cyc/CU == in-flight/latency, exactly).
__global__ __launch_bounds__(256)
void encode_k3(const float* __restrict__ dirs,
               const float* __restrict__ table,
               unsigned* __restrict__ ws,
               int n, LevelParams lp)
{
  int b = blockIdx.x;
  int l0 = b & 7;                     // XCD slot -> levels l0, l0+8
  int chunk = b >> 3;
  int tid = threadIdx.x;

  int ray0 = chunk * 512 + tid;
  int ray1 = ray0 + 256;
  int rcl[2];
  rcl[0] = ray0 < n ? ray0 : n - 1;
  rcl[1] = ray1 < n ? ray1 : n - 1;

  float X[2][3];
  #pragma unroll
  for (int rr = 0; rr < 2; ++rr) {
    X[rr][0] = dirs[rcl[rr] * 3 + 0] * 0.49f + 0.49f;
    X[rr][1] = dirs[rcl[rr] * 3 + 1] * 0.49f + 0.49f;
    X[rr][2] = dirs[rcl[rr] * 3 + 2] * 0.49f + 0.49f;
  }

  unsigned idx[4][8];
  float wa0[4][3], wa1[4][3];
  const float2* tb[4];

  #pragma unroll
  for (int g = 0; g < 4; ++g) {
    int rr = g >> 1;
    int level = l0 + (g & 1) * 8;     // block-uniform -> scalar params
    float s = lp.scale[level];
    unsigned r = lp.res[level];
    bool dense = (lp.dense_mask >> level) & 1u;

    float px = X[rr][0] * s + 0.5f, py = X[rr][1] * s + 0.5f, pz = X[rr][2] * s + 0.5f;
    float gx = floorf(px), gy = floorf(py), gz = floorf(pz);
    float fx = px - gx, fy = py - gy, fz = pz - gz;
    unsigned ix = (unsigned)gx, iy = (unsigned)gy, iz = (unsigned)gz;

    wa1[g][0] = fx * fx * (3.0f - 2.0f * fx);
    wa1[g][1] = fy * fy * (3.0f - 2.0f * fy);
    wa1[g][2] = fz * fz * (3.0f - 2.0f * fz);
    wa0[g][0] = 1.0f - wa1[g][0];
    wa0[g][1] = 1.0f - wa1[g][1];
    wa0[g][2] = 1.0f - wa1[g][2];

    if (dense) {
      unsigned r2 = r * r;
      unsigned x0 = ix, x1 = ix + 1u;
      unsigned y0 = iy * r, y1 = y0 + r;
      unsigned z0 = iz * r2, z1 = z0 + r2;
      idx[g][0] = x0 + y0 + z0; idx[g][1] = x1 + y0 + z0;
      idx[g][2] = x0 + y1 + z0; idx[g][3] = x1 + y1 + z0;
      idx[g][4] = x0 + y0 + z1; idx[g][5] = x1 + y0 + z1;
      idx[g][6] = x0 + y1 + z1; idx[g][7] = x1 + y1 + z1;
    } else {
      unsigned x0 = ix, x1 = ix + 1u;
      unsigned y0 = iy * 2654435761u, y1 = y0 + 2654435761u;  // uint32 wrap == ref
      unsigned z0 = iz * 805459861u,  z1 = z0 + 805459861u;
      idx[g][0] = (x0 ^ y0 ^ z0) & TMASK; idx[g][1] = (x1 ^ y0 ^ z0) & TMASK;
      idx[g][2] = (x0 ^ y1 ^ z0) & TMASK; idx[g][3] = (x1 ^ y1 ^ z0) & TMASK;
      idx[g][4] = (x0 ^ y0 ^ z1) & TMASK; idx[g][5] = (x1 ^ y0 ^ z1) & TMASK;
      idx[g][6] = (x0 ^ y1 ^ z1) & TMASK; idx[g][7] = (x1 ^ y1 ^ z1) & TMASK;
    }
    tb[g] = (const float2*)table + (size_t)level * TSIZE;
  }

  // ---- issue all 32 gathers before any consumption ----
  float2 v[4][8];
  #pragma unroll
  for (int g = 0; g < 4; ++g)
    #pragma unroll
    for (int c = 0; c < 8; ++c)
      v[g][c] = tb[g][idx[g][c]];

  #pragma unroll
  for (int g = 0; g < 4; ++g) {
    float wx0 = wa0[g][0], wx1 = wa1[g][0];
    float wy0 = wa0[g][1], wy1 = wa1[g][1];
    float wz0 = wa0[g][2], wz1 = wa1[g][2];
    float wy0z0 = wy0 * wz0, wy1z0 = wy1 * wz0, wy0z1 = wy0 * wz1, wy1z1 = wy1 * wz1;
    float w000 = wx0 * wy0z0, w100 = wx1 * wy0z0;
    float w010 = wx0 * wy1z0, w110 = wx1 * wy1z0;
    float w001 = wx0 * wy0z1, w101 = wx1 * wy0z1;
    float w011 = wx0 * wy1z1, w111 = wx1 * wy1z1;

    float a0 = w000 * v[g][0].x + w100 * v[g][1].x + w010 * v[g][2].x + w110 * v[g][3].x
             + w001 * v[g][4].x + w101 * v[g][5].x + w011 * v[g][6].x + w111 * v[g][7].x;
    float a1 = w000 * v[g][0].y + w100 * v[g][1].y + w010 * v[g][2].y + w110 * v[g][3].y
             + w001 * v[g][4].y + w101 * v[g][5].y + w011 * v[g][6].y + w111 * v[g][7].y;

    int rr = g >> 1;
    int level = l0 + (g & 1) * 8;
    int ray = (rr == 0) ? ray0 : ray1;
    if (ray < n) {
      unsigned packed = ((unsigned)f2bf(a0) & 0xffffu) | (((unsigned)f2bf(a1) & 0xffffu) << 16);
      ws[(size_t)level * n + ray] = packed;
    }
  }
}

// ============ Kernel 2: MLP via bf16 MFMA (16x16x32), fp32 accumulate. ======
// Input vector PERMUTED to h' = [f0..f31, dx,dy,dz, 0 x29]; W1 rows permuted
// at staging to match. A-fragment (m89 layout: A[m=lane&15][k=q*8+j], q=lane>>4)
// = exactly ws words q*4..q*4+3 of ray (base+nl) -> built in REGISTERS, no LDS
// round-trip for A. H1 C->A transform keeps the barrier-fenced LDS round-trip
// (round-3 lesson: cross-lane LDS needs __syncthreads as a compiler fence).
#define RPB 512
#define ROWS 72   // padded row stride in shorts (144 B = 16B-aligned)

__global__ __launch_bounds__(256)
void mlp_mfma2(const float* __restrict__ dirs,
               const unsigned* __restrict__ ws,   // [16][n] bf16x2 level-major
               const float* __restrict__ W1, const float* __restrict__ b1,
               const float* __restrict__ W2, const float* __restrict__ b2,
               const float* __restrict__ W3, const float* __restrict__ b3,
               float* __restrict__ out, int n)
{
  __shared__ short W1T[64 * ROWS];      // B^T rows [n][k'] bf16, permuted k'
  __shared__ short W2T[64 * ROWS];
  __shared__ short H1T[4][16 * ROWS];   // per-wave hidden tile

  int tid = threadIdx.x;
  // ---- stage weights (once per block) ----
  {
    int nn = tid >> 2;          // output neuron 0..63
    int kg = tid & 3;           // k-group of 16
    bf16x8 v1a, v1b, v2a, v2b;
    #pragma unroll
    for (int j = 0; j < 8; ++j) {
      int k0 = kg * 16 + j, k1 = kg * 16 + 8 + j;
      // W1 permutation: k'<32 -> feature k' (orig row k'+3); 32..34 -> dirs rows 0..2
      v1a[j] = (k0 < 32) ? f2bf(W1[(k0 + 3) * 64 + nn])
             : (k0 < 35) ? f2bf(W1[(k0 - 32) * 64 + nn]) : (short)0;
      v1b[j] = (k1 < 32) ? f2bf(W1[(k1 + 3) * 64 + nn])
             : (k1 < 35) ? f2bf(W1[(k1 - 32) * 64 + nn]) : (short)0;
      v2a[j] = f2bf(W2[k0 * 64 + nn]);
      v2b[j] = f2bf(W2[k1 * 64 + nn]);
    }
    int wo = nn * ROWS + kg * 16;
    *(bf16x8*)&W1T[wo]     = v1a;
    *(bf16x8*)&W1T[wo + 8] = v1b;
    *(bf16x8*)&W2T[wo]     = v2a;
    *(bf16x8*)&W2T[wo + 8] = v2b;
  }
  __syncthreads();

  int wave = tid >> 6, lane = tid & 63;
  int q = lane >> 4, nl = lane & 15;

  float b1v[4], b2v[4], w3v[4];
  #pragma unroll
  for (int t4 = 0; t4 < 4; ++t4) {
    b1v[t4] = b1[t4 * 16 + nl];
    b2v[t4] = b2[t4 * 16 + nl];
    w3v[t4] = W3[t4 * 16 + nl];
  }
  float b3s = b3[0];

  int blockBase = blockIdx.x * RPB;

  for (int batch = 0; batch < RPB / 64; ++batch) {
    int base = blockBase + batch * 64 + wave * 16;
    int rr = base + nl;
    int rc = rr < n ? rr : (n - 1);

    // ---- A fragments in registers (no LDS): words q*4..q*4+3 of ray rc ----
    unsigned u0 = ws[(size_t)(q * 4 + 0) * n + rc];
    unsigned u1 = ws[(size_t)(q * 4 + 1) * n + rc];
    unsigned u2 = ws[(size_t)(q * 4 + 2) * n + rc];
    unsigned u3 = ws[(size_t)(q * 4 + 3) * n + rc];
    bf16x8 a0, a1;
    a0[0] = lo16(u0); a0[1] = hi16(u0); a0[2] = lo16(u1); a0[3] = hi16(u1);
    a0[4] = lo16(u2); a0[5] = hi16(u2); a0[6] = lo16(u3); a0[7] = hi16(u3);
    a1[0] = 0; a1[1] = 0; a1[2] = 0; a1[3] = 0;
    a1[4] = 0; a1[5] = 0; a1[6] = 0; a1[7] = 0;
    if (q == 0) {                       // k'=32..34 are the dirs
      a1[0] = f2bf(dirs[rc * 3 + 0]);
      a1[1] = f2bf(dirs[rc * 3 + 1]);
      a1[2] = f2bf(dirs[rc * 3 + 2]);
    }

    // ---- layer 1: C = A(16x64) * W1'(64->64) ----
    f32x4 acc[4];
    #pragma unroll
    for (int t4 = 0; t4 < 4; ++t4) {
      int brow = (t4 * 16 + nl) * ROWS;
      bf16x8 bt0 = *(const bf16x8*)&W1T[brow + q * 8];
      bf16x8 bt1 = *(const bf16x8*)&W1T[brow + 32 + q * 8];
      f32x4 z = {0.f, 0.f, 0.f, 0.f};
      z = __builtin_amdgcn_mfma_f32_16x16x32_bf16(a0, bt0, z, 0, 0, 0);
      z = __builtin_amdgcn_mfma_f32_16x16x32_bf16(a1, bt1, z, 0, 0, 0);
      acc[t4] = z;
    }
    // bias + relu -> H1 tile (C layout: row=q*4+i, col=t4*16+nl)
    #pragma unroll
    for (int t4 = 0; t4 < 4; ++t4)
      #pragma unroll
      for (int i = 0; i < 4; ++i) {
        float v = fmaxf(acc[t4][i] + b1v[t4], 0.0f);
        H1T[wave][(q * 4 + i) * ROWS + t4 * 16 + nl] = f2bf(v);
      }
    __syncthreads();   // H1 visible + compiler fence

    // ---- layer 2 ----
    bf16x8 h0 = *(const bf16x8*)&H1T[wave][nl * ROWS + q * 8];
    bf16x8 h1f = *(const bf16x8*)&H1T[wave][nl * ROWS + 32 + q * 8];
    #pragma unroll
    for (int t4 = 0; t4 < 4; ++t4) {
      int brow = (t4 * 16 + nl) * ROWS;
      bf16x8 bt0 = *(const bf16x8*)&W2T[brow + q * 8];
      bf16x8 bt1 = *(const bf16x8*)&W2T[brow + 32 + q * 8];
      f32x4 z = {0.f, 0.f, 0.f, 0.f};
      z = __builtin_amdgcn_mfma_f32_16x16x32_bf16(h0, bt0, z, 0, 0, 0);
      z = __builtin_amdgcn_mfma_f32_16x16x32_bf16(h1f, bt1, z, 0, 0, 0);
      acc[t4] = z;
    }

    // ---- layer 3 (fp32): out = softplus(sum_n W3[n]*relu(c2+b2) + b3 + 1) ----
    float part[4] = {0.f, 0.f, 0.f, 0.f};
    #pragma unroll
    for (int t4 = 0; t4 < 4; ++t4)
      #pragma unroll
      for (int i = 0; i < 4; ++i) {
        float v = fmaxf(acc[t4][i] + b2v[t4], 0.0f);
        part[i] = fmaf(v, w3v[t4], part[i]);
      }
    #pragma unroll
    for (int s = 1; s < 16; s <<= 1) {
      #pragma unroll
      for (int i = 0; i < 4; ++i) part[i] += __shfl_xor(part[i], s, 64);
    }
    if (nl == 0) {
      int orow = base + q * 4;
      float ov[4];
      #pragma unroll
      for (int i = 0; i < 4; ++i) {
        float v = part[i] + b3s + 1.0f;
        ov[i] = fmaxf(v, 0.0f) + log1pf(expf(-fabsf(v)));   // softplus
      }
      if (orow + 3 < n) {
        float4 o4; o4.x = ov[0]; o4.y = ov[1]; o4.z = ov[2]; o4.w = ov[3];
        *(float4*)&out[orow] = o4;
      } else {
        for (int i = 0; i < 4; ++i) if (orow + i < n) out[orow + i] = ov[i];
      }
    }
    __syncthreads();   // WAR: next batch's H1T write must not pass these reads
  }
}

// ============ Fallback: round-1 fused kernel (if ws too small) ==============
__global__ __launch_bounds__(256)
void sdf_fused(const float* __restrict__ dirs,
               const float* __restrict__ table,
               const float* __restrict__ W1, const float* __restrict__ b1,
               const float* __restrict__ W2, const float* __restrict__ b2,
               const float* __restrict__ W3, const float* __restrict__ b3,
               float* __restrict__ out, int n, LevelParams lp)
{
  int gid = blockIdx.x * 256 + threadIdx.x;
  if (gid >= n) return;
  float dx = dirs[gid * 3 + 0], dy = dirs[gid * 3 + 1], dz = dirs[gid * 3 + 2];
  float xx = dx * 0.49f + 0.49f, xy = dy * 0.49f + 0.49f, xz = dz * 0.49f + 0.49f;
  float h[35];
  h[0] = dx; h[1] = dy; h[2] = dz;
  #pragma unroll
  for (int l = 0; l < NL; ++l) {
    float s = lp.scale[l];
    float px = xx * s + 0.5f, py = xy * s + 0.5f, pz = xz * s + 0.5f;
    float gx = floorf(px), gy = floorf(py), gz = floorf(pz);
    float fx = px - gx, fy = py - gy, fz = pz - gz;
    unsigned ix = (unsigned)gx, iy = (unsigned)gy, iz = (unsigned)gz;
    float wx1 = fx * fx * (3.0f - 2.0f * fx);
    float wy1 = fy * fy * (3.0f - 2.0f * fy);
    float wz1 = fz * fz * (3.0f - 2.0f * fz);
    float wx0 = 1.0f - wx1, wy0 = 1.0f - wy1, wz0 = 1.0f - wz1;
    unsigned i000, i100, i010, i110, i001, i101, i011, i111;
    if ((lp.dense_mask >> l) & 1u) {
      unsigned r = lp.res[l], r2 = r * r;
      unsigned x0 = ix, x1 = ix + 1u, y0 = iy * r, y1 = y0 + r, z0 = iz * r2, z1 = z0 + r2;
      i000 = x0 + y0 + z0; i100 = x1 + y0 + z0; i010 = x0 + y1 + z0; i110 = x1 + y1 + z0;
      i001 = x0 + y0 + z1; i101 = x1 + y0 + z1; i011 = x0 + y1 + z1; i111 = x1 + y1 + z1;
    } else {
      unsigned x0 = ix, x1 = ix + 1u;
      unsigned y0 = iy * 2654435761u, y1 = y0 + 2654435761u;
      unsigned z0 = iz * 805459861u,  z1 = z0 + 805459861u;
      i000 = (x0 ^ y0 ^ z0) & TMASK; i100 = (x1 ^ y0 ^ z0) & TMASK;
      i010 = (x0 ^ y1 ^ z0) & TMASK; i110 = (x1 ^ y1 ^ z0) & TMASK;
      i001 = (x0 ^ y0 ^ z1) & TMASK; i101 = (x1 ^ y0 ^ z1) & TMASK;
      i011 = (x0 ^ y1 ^ z1) & TMASK; i111 = (x1 ^ y1 ^ z1) & TMASK;
    }
    const float2* t = (const float2*)table + (size_t)l * TSIZE;
    float2 f000 = t[i000], f100 = t[i100], f010 = t[i010], f110 = t[i110];
    float2 f001 = t[i001], f101 = t[i101], f011 = t[i011], f111 = t[i111];
    float wy0z0 = wy0 * wz0, wy1z0 = wy1 * wz0, wy0z1 = wy0 * wz1, wy1z1 = wy1 * wz1;
    float w000 = wx0 * wy0z0, w100 = wx1 * wy0z0, w010 = wx0 * wy1z0, w110 = wx1 * wy1z0;
    float w001 = wx0 * wy0z1, w101 = wx1 * wy0z1, w011 = wx0 * wy1z1, w111 = wx1 * wy1z1;
    h[3 + 2 * l] = w000 * f000.x + w100 * f100.x + w010 * f010.x + w110 * f110.x
                 + w001 * f001.x + w101 * f101.x + w011 * f011.x + w111 * f111.x;
    h[4 + 2 * l] = w000 * f000.y + w100 * f100.y + w010 * f010.y + w110 * f110.y
                 + w001 * f001.y + w101 * f101.y + w011 * f011.y + w111 * f111.y;
  }
  float h1[64];
  #pragma unroll
  for (int j = 0; j < 64; ++j) {
    float acc = b1[j];
    #pragma unroll
    for (int i = 0; i < 35; ++i) acc = fmaf(h[i], W1[i * 64 + j], acc);
    h1[j] = fmaxf(acc, 0.0f);
  }
  float h2[64];
  #pragma unroll
  for (int j = 0; j < 64; ++j) {
    float acc = b2[j];
    #pragma unroll
    for (int i = 0; i < 64; ++i) acc = fmaf(h1[i], W2[i * 64 + j], acc);
    h2[j] = fmaxf(acc, 0.0f);
  }
  float o = b3[0];
  #pragma unroll
  for (int i = 0; i < 64; ++i) o = fmaf(h2[i], W3[i], o);
  float v = o + 1.0f;
  out[gid] = fmaxf(v, 0.0f) + log1pf(expf(-fabsf(v)));
}

extern "C" void kernel_launch(void* const* d_in, const int* in_sizes, int n_in,
                              void* d_out, int out_size, void* d_ws, size_t ws_size,
                              hipStream_t stream) {
  const float* dirs  = (const float*)d_in[0];
  const float* table = (const float*)d_in[1];
  const float* W1 = (const float*)d_in[2];
  const float* b1 = (const float*)d_in[3];
  const float* W2 = (const float*)d_in[4];
  const float* b2 = (const float*)d_in[5];
  const float* W3 = (const float*)d_in[6];
  const float* b3 = (const float*)d_in[7];
  float* out = (float*)d_out;
  int n = in_sizes[0] / 3;

  LevelParams lp;
  double pls = std::exp(std::log(2048.0 / 16.0) / 15.0);
  unsigned dm = 0;
  for (int l = 0; l < NL; ++l) {
    double scale = 16.0 * std::pow(pls, (double)l) - 1.0;
    lp.scale[l] = (float)scale;
    long long res = (long long)std::ceil(scale) + 1;
    lp.res[l] = (unsigned)res;
    if (res * res * res <= (long long)TSIZE) dm |= (1u << l);
  }
  lp.dense_mask = dm;

  size_t feat_bytes = (size_t)n * NL * 4;  // 128 MiB at n=2M
  if (ws_size >= feat_bytes) {
    unsigned* feats = (unsigned*)d_ws;
    int chunks = (n + 511) / 512;
    hipLaunchKernelGGL(encode_k3, dim3(8 * chunks), dim3(256), 0, stream,
                       dirs, table, feats, n, lp);
    int mlp_blocks = (n + RPB - 1) / RPB;
    hipLaunchKernelGGL(mlp_mfma2, dim3(mlp_blocks), dim3(256), 0, stream,
                       dirs, feats, W1, b1, W2, b2, W3, b3, out, n);
  } else {
    int blocks = (n + 255) / 256;
    hipLaunchKernelGGL(sdf_fused, dim3(blocks), dim3(256), 0, stream,
                       dirs, table, W1, b1, W2, b2, W3, b3, out, n, lp);
  }
}

// Round 6
// 1109.305 us; speedup vs baseline: 1.0619x; 1.0619x over previous
//
#include <hip/hip_runtime.h>
#include <hip/hip_bf16.h>
#include <cmath>

#define NL 16
#define TSIZE (1u << 19)
#define TMASK (TSIZE - 1u)

typedef __attribute__((ext_vector_type(8))) short bf16x8;     // 8 bf16 (4 VGPRs)
typedef __attribute__((ext_vector_type(4))) float f32x4;

struct LevelParams {
  float scale[NL];
  unsigned res[NL];
  unsigned dense_mask;
};

static __device__ __forceinline__ short f2bf(float f) {
  __hip_bfloat16 h = __float2bfloat16(f);
  return *reinterpret_cast<short*>(&h);
}
static __device__ __forceinline__ short lo16(unsigned u) { return (short)(u & 0xffffu); }
static __device__ __forceinline__ short hi16(unsigned u) { return (short)(u >> 16); }

// ============ Kernel 1: encode. 1 ray x 2 levels per thread, XCD-pinned. ====
// blockIdx%8 -> XCD (empirical round-robin); levels (k, k+8) pinned to XCD k
// (round-4 verified: FETCH 6.0->1.5 GB). 16 gathers in flight fits the
// register file WITHOUT compiler waitcnt-serialization (round-5 lesson:
// 32 gathers @ 52 VGPRs was silently serialized -> no MLP gain).
__global__ __launch_bounds__(256)
void encode_k4(const float* __restrict__ dirs,
               const float* __restrict__ table,
               unsigned* __restrict__ ws,
               int n, LevelParams lp)
{
  int b = blockIdx.x;
  int l0 = b & 7;                     // XCD slot -> levels l0, l0+8
  int chunk = b >> 3;
  int ray = chunk * 256 + threadIdx.x;
  if (ray >= n) return;

  float X0 = dirs[ray * 3 + 0] * 0.49f + 0.49f;
  float X1 = dirs[ray * 3 + 1] * 0.49f + 0.49f;
  float X2 = dirs[ray * 3 + 2] * 0.49f + 0.49f;

  unsigned idx[2][8];
  float wa0[2][3], wa1[2][3];
  const float2* tb[2];

  #pragma unroll
  for (int g = 0; g < 2; ++g) {
    int level = l0 + g * 8;           // block-uniform -> scalar params
    float s = lp.scale[level];
    unsigned r = lp.res[level];
    bool dense = (lp.dense_mask >> level) & 1u;

    float px = X0 * s + 0.5f, py = X1 * s + 0.5f, pz = X2 * s + 0.5f;
    float gx = floorf(px), gy = floorf(py), gz = floorf(pz);
    float fx = px - gx, fy = py - gy, fz = pz - gz;
    unsigned ix = (unsigned)gx, iy = (unsigned)gy, iz = (unsigned)gz;

    wa1[g][0] = fx * fx * (3.0f - 2.0f * fx);
    wa1[g][1] = fy * fy * (3.0f - 2.0f * fy);
    wa1[g][2] = fz * fz * (3.0f - 2.0f * fz);
    wa0[g][0] = 1.0f - wa1[g][0];
    wa0[g][1] = 1.0f - wa1[g][1];
    wa0[g][2] = 1.0f - wa1[g][2];

    if (dense) {
      unsigned r2 = r * r;
      unsigned x0 = ix, x1 = ix + 1u;
      unsigned y0 = iy * r, y1 = y0 + r;
      unsigned z0 = iz * r2, z1 = z0 + r2;
      idx[g][0] = x0 + y0 + z0; idx[g][1] = x1 + y0 + z0;
      idx[g][2] = x0 + y1 + z0; idx[g][3] = x1 + y1 + z0;
      idx[g][4] = x0 + y0 + z1; idx[g][5] = x1 + y0 + z1;
      idx[g][6] = x0 + y1 + z1; idx[g][7] = x1 + y1 + z1;
    } else {
      unsigned x0 = ix, x1 = ix + 1u;
      unsigned y0 = iy * 2654435761u, y1 = y0 + 2654435761u;  // uint32 wrap == ref
      unsigned z0 = iz * 805459861u,  z1 = z0 + 805459861u;
      idx[g][0] = (x0 ^ y0 ^ z0) & TMASK; idx[g][1] = (x1 ^ y0 ^ z0) & TMASK;
      idx[g][2] = (x0 ^ y1 ^ z0) & TMASK; idx[g][3] = (x1 ^ y1 ^ z0) & TMASK;
      idx[g][4] = (x0 ^ y0 ^ z1) & TMASK; idx[g][5] = (x1 ^ y0 ^ z1) & TMASK;
      idx[g][6] = (x0 ^ y1 ^ z1) & TMASK; idx[g][7] = (x1 ^ y1 ^ z1) & TMASK;
    }
    tb[g] = (const float2*)table + (size_t)level * TSIZE;
  }

  // ---- issue all 16 gathers before any consumption ----
  float2 v[2][8];
  #pragma unroll
  for (int g = 0; g < 2; ++g)
    #pragma unroll
    for (int c = 0; c < 8; ++c)
      v[g][c] = tb[g][idx[g][c]];

  #pragma unroll
  for (int g = 0; g < 2; ++g) {
    float wx0 = wa0[g][0], wx1 = wa1[g][0];
    float wy0 = wa0[g][1], wy1 = wa1[g][1];
    float wz0 = wa0[g][2], wz1 = wa1[g][2];
    float wy0z0 = wy0 * wz0, wy1z0 = wy1 * wz0, wy0z1 = wy0 * wz1, wy1z1 = wy1 * wz1;
    float w000 = wx0 * wy0z0, w100 = wx1 * wy0z0;
    float w010 = wx0 * wy1z0, w110 = wx1 * wy1z0;
    float w001 = wx0 * wy0z1, w101 = wx1 * wy0z1;
    float w011 = wx0 * wy1z1, w111 = wx1 * wy1z1;

    float a0 = w000 * v[g][0].x + w100 * v[g][1].x + w010 * v[g][2].x + w110 * v[g][3].x
             + w001 * v[g][4].x + w101 * v[g][5].x + w011 * v[g][6].x + w111 * v[g][7].x;
    float a1 = w000 * v[g][0].y + w100 * v[g][1].y + w010 * v[g][2].y + w110 * v[g][3].y
             + w001 * v[g][4].y + w101 * v[g][5].y + w011 * v[g][6].y + w111 * v[g][7].y;

    int level = l0 + g * 8;
    unsigned packed = ((unsigned)f2bf(a0) & 0xffffu) | (((unsigned)f2bf(a1) & 0xffffu) << 16);
    ws[(size_t)level * n + ray] = packed;
  }
}

// ============ Kernel 2: MLP via bf16 MFMA (16x16x32), fp32 accumulate. ======
// Input PERMUTED to h' = [f0..f31, dx,dy,dz, 0 x29]; W1 rows permuted at
// staging. A-fragments built in registers from ws (m89 layout:
// A[m=lane&15][k=q*8+j], q=lane>>4). 2 tiles (32 rays) per wave per batch:
// halves barrier/epilogue overhead per ray, 2x MFMA ILP. H1 C->A transform
// via barrier-fenced LDS (round-3 lesson: cross-lane LDS needs __syncthreads
// as a compiler fence).
#define RPB 512
#define ROWS 72   // padded row stride in shorts (144 B = 16B-aligned)

__global__ __launch_bounds__(256)
void mlp_mfma3(const float* __restrict__ dirs,
               const unsigned* __restrict__ ws,   // [16][n] bf16x2 level-major
               const float* __restrict__ W1, const float* __restrict__ b1,
               const float* __restrict__ W2, const float* __restrict__ b2,
               const float* __restrict__ W3, const float* __restrict__ b3,
               float* __restrict__ out, int n)
{
  __shared__ short W1T[64 * ROWS];      // B^T rows [n][k'] bf16, permuted k'
  __shared__ short W2T[64 * ROWS];
  __shared__ short H1T[4][32 * ROWS];   // per-wave hidden tile (32 rays)

  int tid = threadIdx.x;
  // ---- stage weights (once per block) ----
  {
    int nn = tid >> 2;          // output neuron 0..63
    int kg = tid & 3;           // k-group of 16
    bf16x8 v1a, v1b, v2a, v2b;
    #pragma unroll
    for (int j = 0; j < 8; ++j) {
      int k0 = kg * 16 + j, k1 = kg * 16 + 8 + j;
      // W1 permutation: k'<32 -> feature k' (orig row k'+3); 32..34 -> dirs rows 0..2
      v1a[j] = (k0 < 32) ? f2bf(W1[(k0 + 3) * 64 + nn])
             : (k0 < 35) ? f2bf(W1[(k0 - 32) * 64 + nn]) : (short)0;
      v1b[j] = (k1 < 32) ? f2bf(W1[(k1 + 3) * 64 + nn])
             : (k1 < 35) ? f2bf(W1[(k1 - 32) * 64 + nn]) : (short)0;
      v2a[j] = f2bf(W2[k0 * 64 + nn]);
      v2b[j] = f2bf(W2[k1 * 64 + nn]);
    }
    int wo = nn * ROWS + kg * 16;
    *(bf16x8*)&W1T[wo]     = v1a;
    *(bf16x8*)&W1T[wo + 8] = v1b;
    *(bf16x8*)&W2T[wo]     = v2a;
    *(bf16x8*)&W2T[wo + 8] = v2b;
  }
  __syncthreads();

  int wave = tid >> 6, lane = tid & 63;
  int q = lane >> 4, nl = lane & 15;

  float b1v[4], b2v[4], w3v[4];
  #pragma unroll
  for (int t4 = 0; t4 < 4; ++t4) {
    b1v[t4] = b1[t4 * 16 + nl];
    b2v[t4] = b2[t4 * 16 + nl];
    w3v[t4] = W3[t4 * 16 + nl];
  }
  float b3s = b3[0];

  int blockBase = blockIdx.x * RPB;

  for (int batch = 0; batch < RPB / 128; ++batch) {
    int wbase = blockBase + batch * 128 + wave * 32;   // 32 rays per wave

    // ---- A fragments in registers for both 16-ray tiles ----
    bf16x8 a0[2], a1[2];
    #pragma unroll
    for (int t = 0; t < 2; ++t) {
      int rr = wbase + t * 16 + nl;
      int rc = rr < n ? rr : (n - 1);
      unsigned u0 = ws[(size_t)(q * 4 + 0) * n + rc];
      unsigned u1 = ws[(size_t)(q * 4 + 1) * n + rc];
      unsigned u2 = ws[(size_t)(q * 4 + 2) * n + rc];
      unsigned u3 = ws[(size_t)(q * 4 + 3) * n + rc];
      a0[t][0] = lo16(u0); a0[t][1] = hi16(u0); a0[t][2] = lo16(u1); a0[t][3] = hi16(u1);
      a0[t][4] = lo16(u2); a0[t][5] = hi16(u2); a0[t][6] = lo16(u3); a0[t][7] = hi16(u3);
      a1[t][0] = 0; a1[t][1] = 0; a1[t][2] = 0; a1[t][3] = 0;
      a1[t][4] = 0; a1[t][5] = 0; a1[t][6] = 0; a1[t][7] = 0;
      if (q == 0) {                     // k'=32..34 are the dirs
        a1[t][0] = f2bf(dirs[rc * 3 + 0]);
        a1[t][1] = f2bf(dirs[rc * 3 + 1]);
        a1[t][2] = f2bf(dirs[rc * 3 + 2]);
      }
    }

    // ---- layer 1 ----
    f32x4 acc[2][4];
    #pragma unroll
    for (int t4 = 0; t4 < 4; ++t4) {
      int brow = (t4 * 16 + nl) * ROWS;
      bf16x8 bt0 = *(const bf16x8*)&W1T[brow + q * 8];
      bf16x8 bt1 = *(const bf16x8*)&W1T[brow + 32 + q * 8];
      #pragma unroll
      for (int t = 0; t < 2; ++t) {
        f32x4 z = {0.f, 0.f, 0.f, 0.f};
        z = __builtin_amdgcn_mfma_f32_16x16x32_bf16(a0[t], bt0, z, 0, 0, 0);
        z = __builtin_amdgcn_mfma_f32_16x16x32_bf16(a1[t], bt1, z, 0, 0, 0);
        acc[t][t4] = z;
      }
    }
    // bias + relu -> H1 tile (C layout: ray-row = t*16 + q*4+i, col = t4*16+nl)
    #pragma unroll
    for (int t = 0; t < 2; ++t)
      #pragma unroll
      for (int t4 = 0; t4 < 4; ++t4)
        #pragma unroll
        for (int i = 0; i < 4; ++i) {
          float v = fmaxf(acc[t][t4][i] + b1v[t4], 0.0f);
          H1T[wave][(t * 16 + q * 4 + i) * ROWS + t4 * 16 + nl] = f2bf(v);
        }
    __syncthreads();   // H1 visible + compiler fence

    // ---- layer 2 ----
    #pragma unroll
    for (int t4 = 0; t4 < 4; ++t4) {
      int brow = (t4 * 16 + nl) * ROWS;
      bf16x8 bt0 = *(const bf16x8*)&W2T[brow + q * 8];
      bf16x8 bt1 = *(const bf16x8*)&W2T[brow + 32 + q * 8];
      #pragma unroll
      for (int t = 0; t < 2; ++t) {
        bf16x8 h0 = *(const bf16x8*)&H1T[wave][(t * 16 + nl) * ROWS + q * 8];
        bf16x8 h1f = *(const bf16x8*)&H1T[wave][(t * 16 + nl) * ROWS + 32 + q * 8];
        f32x4 z = {0.f, 0.f, 0.f, 0.f};
        z = __builtin_amdgcn_mfma_f32_16x16x32_bf16(h0, bt0, z, 0, 0, 0);
        z = __builtin_amdgcn_mfma_f32_16x16x32_bf16(h1f, bt1, z, 0, 0, 0);
        acc[t][t4] = z;
      }
    }

    // ---- layer 3 (fp32): out = softplus(sum_n W3[n]*relu(c2+b2) + b3 + 1) ----
    #pragma unroll
    for (int t = 0; t < 2; ++t) {
      float part[4] = {0.f, 0.f, 0.f, 0.f};
      #pragma unroll
      for (int t4 = 0; t4 < 4; ++t4)
        #pragma unroll
        for (int i = 0; i < 4; ++i) {
          float v = fmaxf(acc[t][t4][i] + b2v[t4], 0.0f);
          part[i] = fmaf(v, w3v[t4], part[i]);
        }
      #pragma unroll
      for (int s = 1; s < 16; s <<= 1) {
        #pragma unroll
        for (int i = 0; i < 4; ++i) part[i] += __shfl_xor(part[i], s, 64);
      }
      if (nl == 0) {
        int orow = wbase + t * 16 + q * 4;
        float ov[4];
        #pragma unroll
        for (int i = 0; i < 4; ++i) {
          float v = part[i] + b3s + 1.0f;
          ov[i] = fmaxf(v, 0.0f) + log1pf(expf(-fabsf(v)));   // softplus
        }
        if (orow + 3 < n) {
          float4 o4; o4.x = ov[0]; o4.y = ov[1]; o4.z = ov[2]; o4.w = ov[3];
          *(float4*)&out[orow] = o4;
        } else {
          for (int i = 0; i < 4; ++i) if (orow + i < n) out[orow + i] = ov[i];
        }
      }
    }
    __syncthreads();   // WAR: next batch's H1T write must not pass these reads
  }
}

// ============ Fallback: round-1 fused kernel (if ws too small) ==============
__global__ __launch_bounds__(256)
void sdf_fused(const float* __restrict__ dirs,
               const float* __restrict__ table,
               const float* __restrict__ W1, const float* __restrict__ b1,
               const float* __restrict__ W2, const float* __restrict__ b2,
               const float* __restrict__ W3, const float* __restrict__ b3,
               float* __restrict__ out, int n, LevelParams lp)
{
  int gid = blockIdx.x * 256 + threadIdx.x;
  if (gid >= n) return;
  float dx = dirs[gid * 3 + 0], dy = dirs[gid * 3 + 1], dz = dirs[gid * 3 + 2];
  float xx = dx * 0.49f + 0.49f, xy = dy * 0.49f + 0.49f, xz = dz * 0.49f + 0.49f;
  float h[35];
  h[0] = dx; h[1] = dy; h[2] = dz;
  #pragma unroll
  for (int l = 0; l < NL; ++l) {
    float s = lp.scale[l];
    float px = xx * s + 0.5f, py = xy * s + 0.5f, pz = xz * s + 0.5f;
    float gx = floorf(px), gy = floorf(py), gz = floorf(pz);
    float fx = px - gx, fy = py - gy, fz = pz - gz;
    unsigned ix = (unsigned)gx, iy = (unsigned)gy, iz = (unsigned)gz;
    float wx1 = fx * fx * (3.0f - 2.0f * fx);
    float wy1 = fy * fy * (3.0f - 2.0f * fy);
    float wz1 = fz * fz * (3.0f - 2.0f * fz);
    float wx0 = 1.0f - wx1, wy0 = 1.0f - wy1, wz0 = 1.0f - wz1;
    unsigned i000, i100, i010, i110, i001, i101, i011, i111;
    if ((lp.dense_mask >> l) & 1u) {
      unsigned r = lp.res[l], r2 = r * r;
      unsigned x0 = ix, x1 = ix + 1u, y0 = iy * r, y1 = y0 + r, z0 = iz * r2, z1 = z0 + r2;
      i000 = x0 + y0 + z0; i100 = x1 + y0 + z0; i010 = x0 + y1 + z0; i110 = x1 + y1 + z0;
      i001 = x0 + y0 + z1; i101 = x1 + y0 + z1; i011 = x0 + y1 + z1; i111 = x1 + y1 + z1;
    } else {
      unsigned x0 = ix, x1 = ix + 1u;
      unsigned y0 = iy * 2654435761u, y1 = y0 + 2654435761u;
      unsigned z0 = iz * 805459861u,  z1 = z0 + 805459861u;
      i000 = (x0 ^ y0 ^ z0) & TMASK; i100 = (x1 ^ y0 ^ z0) & TMASK;
      i010 = (x0 ^ y1 ^ z0) & TMASK; i110 = (x1 ^ y1 ^ z0) & TMASK;
      i001 = (x0 ^ y0 ^ z1) & TMASK; i101 = (x1 ^ y0 ^ z1) & TMASK;
      i011 = (x0 ^ y1 ^ z1) & TMASK; i111 = (x1 ^ y1 ^ z1) & TMASK;
    }
    const float2* t = (const float2*)table + (size_t)l * TSIZE;
    float2 f000 = t[i000], f100 = t[i100], f010 = t[i010], f110 = t[i110];
    float2 f001 = t[i001], f101 = t[i101], f011 = t[i011], f111 = t[i111];
    float wy0z0 = wy0 * wz0, wy1z0 = wy1 * wz0, wy0z1 = wy0 * wz1, wy1z1 = wy1 * wz1;
    float w000 = wx0 * wy0z0, w100 = wx1 * wy0z0, w010 = wx0 * wy1z0, w110 = wx1 * wy1z0;
    float w001 = wx0 * wy0z1, w101 = wx1 * wy0z1, w011 = wx0 * wy1z1, w111 = wx1 * wy1z1;
    h[3 + 2 * l] = w000 * f000.x + w100 * f100.x + w010 * f010.x + w110 * f110.x
                 + w001 * f001.x + w101 * f101.x + w011 * f011.x + w111 * f111.x;
    h[4 + 2 * l] = w000 * f000.y + w100 * f100.y + w010 * f010.y + w110 * f110.y
                 + w001 * f001.y + w101 * f101.y + w011 * f011.y + w111 * f111.y;
  }
  float h1[64];
  #pragma unroll
  for (int j = 0; j < 64; ++j) {
    float acc = b1[j];
    #pragma unroll
    for (int i = 0; i < 35; ++i) acc = fmaf(h[i], W1[i * 64 + j], acc);
    h1[j] = fmaxf(acc, 0.0f);
  }
  float h2[64];
  #pragma unroll
  for (int j = 0; j < 64; ++j) {
    float acc = b2[j];
    #pragma unroll
    for (int i = 0; i < 64; ++i) acc = fmaf(h1[i], W2[i * 64 + j], acc);
    h2[j] = fmaxf(acc, 0.0f);
  }
  float o = b3[0];
  #pragma unroll
  for (int i = 0; i < 64; ++i) o = fmaf(h2[i], W3[i], o);
  float v = o + 1.0f;
  out[gid] = fmaxf(v, 0.0f) + log1pf(expf(-fabsf(v)));
}

extern "C" void kernel_launch(void* const* d_in, const int* in_sizes, int n_in,
                              void* d_out, int out_size, void* d_ws, size_t ws_size,
                              hipStream_t stream) {
  const float* dirs  = (const float*)d_in[0];
  const float* table = (const float*)d_in[1];
  const float* W1 = (const float*)d_in[2];
  const float* b1 = (const float*)d_in[3];
  const float* W2 = (const float*)d_in[4];
  const float* b2 = (const float*)d_in[5];
  const float* W3 = (const float*)d_in[6];
  const float* b3 = (const float*)d_in[7];
  float* out = (float*)d_out;
  int n = in_sizes[0] / 3;

  LevelParams lp;
  double pls = std::exp(std::log(2048.0 / 16.0) / 15.0);
  unsigned dm = 0;
  for (int l = 0; l < NL; ++l) {
    double scale = 16.0 * std::pow(pls, (double)l) - 1.0;
    lp.scale[l] = (float)scale;
    long long res = (long long)std::ceil(scale) + 1;
    lp.res[l] = (unsigned)res;
    if (res * res * res <= (long long)TSIZE) dm |= (1u << l);
  }
  lp.dense_mask = dm;

  size_t feat_bytes = (size_t)n * NL * 4;  // 128 MiB at n=2M
  if (ws_size >= feat_bytes) {
    unsigned* feats = (unsigned*)d_ws;
    int chunks = (n + 255) / 256;
    hipLaunchKernelGGL(encode_k4, dim3(8 * chunks), dim3(256), 0, stream,
                       dirs, table, feats, n, lp);
    int mlp_blocks = (n + RPB - 1) / RPB;
    hipLaunchKernelGGL(mlp_mfma3, dim3(mlp_blocks), dim3(256), 0, stream,
                       dirs, feats, W1, b1, W2, b2, W3, b3, out, n);
  } else {
    int blocks = (n + 255) / 256;
    hipLaunchKernelGGL(sdf_fused, dim3(blocks), dim3(256), 0, stream,
                       dirs, table, W1, b1, W2, b2, W3, b3, out, n, lp);
  }
}

// Round 7
// 951.008 us; speedup vs baseline: 1.2387x; 1.1665x over previous
//
#include <hip/hip_runtime.h>
#include <hip/hip_bf16.h>
#include <cmath>

#define NL 16
#define TSIZE (1u << 19)
#define TMASK (TSIZE - 1u)

typedef __attribute__((ext_vector_type(8))) short bf16x8;     // 8 bf16 (4 VGPRs)
typedef __attribute__((ext_vector_type(4))) float f32x4;

struct LevelParams {
  float scale[NL];
  unsigned res[NL];
  unsigned dense_mask;
};

static __device__ __forceinline__ short f2bf(float f) {
  __hip_bfloat16 h = __float2bfloat16(f);
  return *reinterpret_cast<short*>(&h);
}
static __device__ __forceinline__ short lo16(unsigned u) { return (short)(u & 0xffffu); }
static __device__ __forceinline__ short hi16(unsigned u) { return (short)(u >> 16); }

// ============ Kernel 1: encode. 1 ray x 2 levels per thread, XCD-pinned. ====
// blockIdx%8 -> XCD (empirical round-robin); levels (k, k+8) pinned to XCD k
// (round-4 verified: FETCH 6.0->1.5 GB). Round-6 model: throughput is capped
// at ~0.5 vector-memory REQUESTS/cyc/CU (invariant across occupancy 35-71%),
// so the lever is request count. Hashed x-corner pair is ALWAYS {2m, 2m+1}
// (PRIME_x = 1: q = p^1), so one aligned float4 covers both corners ->
// hashed levels: 4 requests instead of 8. Requests/ray: 128 -> 84.
__global__ __launch_bounds__(256)
void encode_k5(const float* __restrict__ dirs,
               const float* __restrict__ table,
               unsigned* __restrict__ ws,
               int n, LevelParams lp)
{
  int b = blockIdx.x;
  int l0 = b & 7;                     // XCD slot -> levels l0, l0+8
  int chunk = b >> 3;
  int ray = chunk * 256 + threadIdx.x;
  if (ray >= n) return;

  float X0 = dirs[ray * 3 + 0] * 0.49f + 0.49f;
  float X1 = dirs[ray * 3 + 1] * 0.49f + 0.49f;
  float X2 = dirs[ray * 3 + 2] * 0.49f + 0.49f;

  float wa0[2][3], wa1[2][3];
  bool dns[2];
  unsigned didx[2][8];                // dense: 8 float2 entry indices
  unsigned par[2][4];                 // hashed: parity of x0-corner index
  const float2* tb[2];

  #pragma unroll
  for (int g = 0; g < 2; ++g) {
    int level = l0 + g * 8;           // block-uniform -> scalar params
    float s = lp.scale[level];
    unsigned r = lp.res[level];
    dns[g] = (lp.dense_mask >> level) & 1u;

    float px = X0 * s + 0.5f, py = X1 * s + 0.5f, pz = X2 * s + 0.5f;
    float gx = floorf(px), gy = floorf(py), gz = floorf(pz);
    float fx = px - gx, fy = py - gy, fz = pz - gz;
    unsigned ix = (unsigned)gx, iy = (unsigned)gy, iz = (unsigned)gz;

    wa1[g][0] = fx * fx * (3.0f - 2.0f * fx);
    wa1[g][1] = fy * fy * (3.0f - 2.0f * fy);
    wa1[g][2] = fz * fz * (3.0f - 2.0f * fz);
    wa0[g][0] = 1.0f - wa1[g][0];
    wa0[g][1] = 1.0f - wa1[g][1];
    wa0[g][2] = 1.0f - wa1[g][2];

    if (dns[g]) {
      unsigned r2 = r * r;
      unsigned x0 = ix, x1 = ix + 1u;
      unsigned y0 = iy * r, y1 = y0 + r;
      unsigned z0 = iz * r2, z1 = z0 + r2;
      didx[g][0] = x0 + y0 + z0; didx[g][1] = x1 + y0 + z0;
      didx[g][2] = x0 + y1 + z0; didx[g][3] = x1 + y1 + z0;
      didx[g][4] = x0 + y0 + z1; didx[g][5] = x1 + y0 + z1;
      didx[g][6] = x0 + y1 + z1; didx[g][7] = x1 + y1 + z1;
    } else {
      unsigned y0 = iy * 2654435761u, y1 = y0 + 2654435761u;  // uint32 wrap == ref
      unsigned z0 = iz * 805459861u,  z1 = z0 + 805459861u;
      // x0-corner indices for the 4 (y,z) combos; x1-corner is p^1 (PRIME_x=1)
      unsigned p0 = (ix ^ y0 ^ z0) & TMASK;
      unsigned p1 = (ix ^ y1 ^ z0) & TMASK;
      unsigned p2 = (ix ^ y0 ^ z1) & TMASK;
      unsigned p3 = (ix ^ y1 ^ z1) & TMASK;
      // reuse didx[0..3] as the aligned PAIR index (p>>1)
      didx[g][0] = p0 >> 1; didx[g][1] = p1 >> 1;
      didx[g][2] = p2 >> 1; didx[g][3] = p3 >> 1;
      par[g][0] = p0 & 1u; par[g][1] = p1 & 1u;
      par[g][2] = p2 & 1u; par[g][3] = p3 & 1u;
    }
    tb[g] = (const float2*)table + (size_t)level * TSIZE;
  }

  // ---- issue all loads before any consumption ----
  float2 v[2][8];
  float4 f4[2][4];
  #pragma unroll
  for (int g = 0; g < 2; ++g) {
    if (dns[g]) {
      #pragma unroll
      for (int c = 0; c < 8; ++c) v[g][c] = tb[g][didx[g][c]];
    } else {
      const float4* t4p = (const float4*)tb[g];   // pair i = entries {2i, 2i+1}
      #pragma unroll
      for (int c = 0; c < 4; ++c) f4[g][c] = t4p[didx[g][c]];
    }
  }
  // ---- unpack hashed pairs: corner(x0)=entry p, corner(x1)=entry p^1 ----
  #pragma unroll
  for (int g = 0; g < 2; ++g) {
    if (!dns[g]) {
      #pragma unroll
      for (int c = 0; c < 4; ++c) {
        float2 even, odd;
        even.x = f4[g][c].x; even.y = f4[g][c].y;   // entry 2m
        odd.x  = f4[g][c].z; odd.y  = f4[g][c].w;   // entry 2m+1
        bool o = par[g][c] != 0;
        v[g][2 * c]     = o ? odd : even;           // x0 corner (index p)
        v[g][2 * c + 1] = o ? even : odd;           // x1 corner (index p^1)
      }
    }
  }

  #pragma unroll
  for (int g = 0; g < 2; ++g) {
    float wx0 = wa0[g][0], wx1 = wa1[g][0];
    float wy0 = wa0[g][1], wy1 = wa1[g][1];
    float wz0 = wa0[g][2], wz1 = wa1[g][2];
    float wy0z0 = wy0 * wz0, wy1z0 = wy1 * wz0, wy0z1 = wy0 * wz1, wy1z1 = wy1 * wz1;
    // v order: [y0z0:x0,x1][y1z0:x0,x1][y0z1:x0,x1][y1z1:x0,x1]
    float w000 = wx0 * wy0z0, w100 = wx1 * wy0z0;
    float w010 = wx0 * wy1z0, w110 = wx1 * wy1z0;
    float w001 = wx0 * wy0z1, w101 = wx1 * wy0z1;
    float w011 = wx0 * wy1z1, w111 = wx1 * wy1z1;

    float a0 = w000 * v[g][0].x + w100 * v[g][1].x + w010 * v[g][2].x + w110 * v[g][3].x
             + w001 * v[g][4].x + w101 * v[g][5].x + w011 * v[g][6].x + w111 * v[g][7].x;
    float a1 = w000 * v[g][0].y + w100 * v[g][1].y + w010 * v[g][2].y + w110 * v[g][3].y
             + w001 * v[g][4].y + w101 * v[g][5].y + w011 * v[g][6].y + w111 * v[g][7].y;

    int level = l0 + g * 8;
    unsigned packed = ((unsigned)f2bf(a0) & 0xffffu) | (((unsigned)f2bf(a1) & 0xffffu) << 16);
    ws[(size_t)level * n + ray] = packed;
  }
}

// ============ Kernel 2: MLP via bf16 MFMA (16x16x32), fp32 accumulate. ======
// (unchanged from round 6 — verified correct; ~245 us, revisit after encode)
#define RPB 512
#define ROWS 72   // padded row stride in shorts (144 B = 16B-aligned)

__global__ __launch_bounds__(256)
void mlp_mfma3(const float* __restrict__ dirs,
               const unsigned* __restrict__ ws,   // [16][n] bf16x2 level-major
               const float* __restrict__ W1, const float* __restrict__ b1,
               const float* __restrict__ W2, const float* __restrict__ b2,
               const float* __restrict__ W3, const float* __restrict__ b3,
               float* __restrict__ out, int n)
{
  __shared__ short W1T[64 * ROWS];      // B^T rows [n][k'] bf16, permuted k'
  __shared__ short W2T[64 * ROWS];
  __shared__ short H1T[4][32 * ROWS];   // per-wave hidden tile (32 rays)

  int tid = threadIdx.x;
  {
    int nn = tid >> 2;          // output neuron 0..63
    int kg = tid & 3;           // k-group of 16
    bf16x8 v1a, v1b, v2a, v2b;
    #pragma unroll
    for (int j = 0; j < 8; ++j) {
      int k0 = kg * 16 + j, k1 = kg * 16 + 8 + j;
      // W1 permutation: k'<32 -> feature k' (orig row k'+3); 32..34 -> dirs rows 0..2
      v1a[j] = (k0 < 32) ? f2bf(W1[(k0 + 3) * 64 + nn])
             : (k0 < 35) ? f2bf(W1[(k0 - 32) * 64 + nn]) : (short)0;
      v1b[j] = (k1 < 32) ? f2bf(W1[(k1 + 3) * 64 + nn])
             : (k1 < 35) ? f2bf(W1[(k1 - 32) * 64 + nn]) : (short)0;
      v2a[j] = f2bf(W2[k0 * 64 + nn]);
      v2b[j] = f2bf(W2[k1 * 64 + nn]);
    }
    int wo = nn * ROWS + kg * 16;
    *(bf16x8*)&W1T[wo]     = v1a;
    *(bf16x8*)&W1T[wo + 8] = v1b;
    *(bf16x8*)&W2T[wo]     = v2a;
    *(bf16x8*)&W2T[wo + 8] = v2b;
  }
  __syncthreads();

  int wave = tid >> 6, lane = tid & 63;
  int q = lane >> 4, nl = lane & 15;

  float b1v[4], b2v[4], w3v[4];
  #pragma unroll
  for (int t4 = 0; t4 < 4; ++t4) {
    b1v[t4] = b1[t4 * 16 + nl];
    b2v[t4] = b2[t4 * 16 + nl];
    w3v[t4] = W3[t4 * 16 + nl];
  }
  float b3s = b3[0];

  int blockBase = blockIdx.x * RPB;

  for (int batch = 0; batch < RPB / 128; ++batch) {
    int wbase = blockBase + batch * 128 + wave * 32;   // 32 rays per wave

    bf16x8 a0[2], a1[2];
    #pragma unroll
    for (int t = 0; t < 2; ++t) {
      int rr = wbase + t * 16 + nl;
      int rc = rr < n ? rr : (n - 1);
      unsigned u0 = ws[(size_t)(q * 4 + 0) * n + rc];
      unsigned u1 = ws[(size_t)(q * 4 + 1) * n + rc];
      unsigned u2 = ws[(size_t)(q * 4 + 2) * n + rc];
      unsigned u3 = ws[(size_t)(q * 4 + 3) * n + rc];
      a0[t][0] = lo16(u0); a0[t][1] = hi16(u0); a0[t][2] = lo16(u1); a0[t][3] = hi16(u1);
      a0[t][4] = lo16(u2); a0[t][5] = hi16(u2); a0[t][6] = lo16(u3); a0[t][7] = hi16(u3);
      a1[t][0] = 0; a1[t][1] = 0; a1[t][2] = 0; a1[t][3] = 0;
      a1[t][4] = 0; a1[t][5] = 0; a1[t][6] = 0; a1[t][7] = 0;
      if (q == 0) {                     // k'=32..34 are the dirs
        a1[t][0] = f2bf(dirs[rc * 3 + 0]);
        a1[t][1] = f2bf(dirs[rc * 3 + 1]);
        a1[t][2] = f2bf(dirs[rc * 3 + 2]);
      }
    }

    f32x4 acc[2][4];
    #pragma unroll
    for (int t4 = 0; t4 < 4; ++t4) {
      int brow = (t4 * 16 + nl) * ROWS;
      bf16x8 bt0 = *(const bf16x8*)&W1T[brow + q * 8];
      bf16x8 bt1 = *(const bf16x8*)&W1T[brow + 32 + q * 8];
      #pragma unroll
      for (int t = 0; t < 2; ++t) {
        f32x4 z = {0.f, 0.f, 0.f, 0.f};
        z = __builtin_amdgcn_mfma_f32_16x16x32_bf16(a0[t], bt0, z, 0, 0, 0);
        z = __builtin_amdgcn_mfma_f32_16x16x32_bf16(a1[t], bt1, z, 0, 0, 0);
        acc[t][t4] = z;
      }
    }
    #pragma unroll
    for (int t = 0; t < 2; ++t)
      #pragma unroll
      for (int t4 = 0; t4 < 4; ++t4)
        #pragma unroll
        for (int i = 0; i < 4; ++i) {
          float v = fmaxf(acc[t][t4][i] + b1v[t4], 0.0f);
          H1T[wave][(t * 16 + q * 4 + i) * ROWS + t4 * 16 + nl] = f2bf(v);
        }
    __syncthreads();   // H1 visible + compiler fence

    #pragma unroll
    for (int t4 = 0; t4 < 4; ++t4) {
      int brow = (t4 * 16 + nl) * ROWS;
      bf16x8 bt0 = *(const bf16x8*)&W2T[brow + q * 8];
      bf16x8 bt1 = *(const bf16x8*)&W2T[brow + 32 + q * 8];
      #pragma unroll
      for (int t = 0; t < 2; ++t) {
        bf16x8 h0 = *(const bf16x8*)&H1T[wave][(t * 16 + nl) * ROWS + q * 8];
        bf16x8 h1f = *(const bf16x8*)&H1T[wave][(t * 16 + nl) * ROWS + 32 + q * 8];
        f32x4 z = {0.f, 0.f, 0.f, 0.f};
        z = __builtin_amdgcn_mfma_f32_16x16x32_bf16(h0, bt0, z, 0, 0, 0);
        z = __builtin_amdgcn_mfma_f32_16x16x32_bf16(h1f, bt1, z, 0, 0, 0);
        acc[t][t4] = z;
      }
    }

    #pragma unroll
    for (int t = 0; t < 2; ++t) {
      float part[4] = {0.f, 0.f, 0.f, 0.f};
      #pragma unroll
      for (int t4 = 0; t4 < 4; ++t4)
        #pragma unroll
        for (int i = 0; i < 4; ++i) {
          float v = fmaxf(acc[t][t4][i] + b2v[t4], 0.0f);
          part[i] = fmaf(v, w3v[t4], part[i]);
        }
      #pragma unroll
      for (int s = 1; s < 16; s <<= 1) {
        #pragma unroll
        for (int i = 0; i < 4; ++i) part[i] += __shfl_xor(part[i], s, 64);
      }
      if (nl == 0) {
        int orow = wbase + t * 16 + q * 4;
        float ov[4];
        #pragma unroll
        for (int i = 0; i < 4; ++i) {
          float v = part[i] + b3s + 1.0f;
          ov[i] = fmaxf(v, 0.0f) + log1pf(expf(-fabsf(v)));   // softplus
        }
        if (orow + 3 < n) {
          float4 o4; o4.x = ov[0]; o4.y = ov[1]; o4.z = ov[2]; o4.w = ov[3];
          *(float4*)&out[orow] = o4;
        } else {
          for (int i = 0; i < 4; ++i) if (orow + i < n) out[orow + i] = ov[i];
        }
      }
    }
    __syncthreads();   // WAR: next batch's H1T write must not pass these reads
  }
}

// ============ Fallback: round-1 fused kernel (if ws too small) ==============
__global__ __launch_bounds__(256)
void sdf_fused(const float* __restrict__ dirs,
               const float* __restrict__ table,
               const float* __restrict__ W1, const float* __restrict__ b1,
               const float* __restrict__ W2, const float* __restrict__ b2,
               const float* __restrict__ W3, const float* __restrict__ b3,
               float* __restrict__ out, int n, LevelParams lp)
{
  int gid = blockIdx.x * 256 + threadIdx.x;
  if (gid >= n) return;
  float dx = dirs[gid * 3 + 0], dy = dirs[gid * 3 + 1], dz = dirs[gid * 3 + 2];
  float xx = dx * 0.49f + 0.49f, xy = dy * 0.49f + 0.49f, xz = dz * 0.49f + 0.49f;
  float h[35];
  h[0] = dx; h[1] = dy; h[2] = dz;
  #pragma unroll
  for (int l = 0; l < NL; ++l) {
    float s = lp.scale[l];
    float px = xx * s + 0.5f, py = xy * s + 0.5f, pz = xz * s + 0.5f;
    float gx = floorf(px), gy = floorf(py), gz = floorf(pz);
    float fx = px - gx, fy = py - gy, fz = pz - gz;
    unsigned ix = (unsigned)gx, iy = (unsigned)gy, iz = (unsigned)gz;
    float wx1 = fx * fx * (3.0f - 2.0f * fx);
    float wy1 = fy * fy * (3.0f - 2.0f * fy);
    float wz1 = fz * fz * (3.0f - 2.0f * fz);
    float wx0 = 1.0f - wx1, wy0 = 1.0f - wy1, wz0 = 1.0f - wz1;
    unsigned i000, i100, i010, i110, i001, i101, i011, i111;
    if ((lp.dense_mask >> l) & 1u) {
      unsigned r = lp.res[l], r2 = r * r;
      unsigned x0 = ix, x1 = ix + 1u, y0 = iy * r, y1 = y0 + r, z0 = iz * r2, z1 = z0 + r2;
      i000 = x0 + y0 + z0; i100 = x1 + y0 + z0; i010 = x0 + y1 + z0; i110 = x1 + y1 + z0;
      i001 = x0 + y0 + z1; i101 = x1 + y0 + z1; i011 = x0 + y1 + z1; i111 = x1 + y1 + z1;
    } else {
      unsigned x0 = ix, x1 = ix + 1u;
      unsigned y0 = iy * 2654435761u, y1 = y0 + 2654435761u;
      unsigned z0 = iz * 805459861u,  z1 = z0 + 805459861u;
      i000 = (x0 ^ y0 ^ z0) & TMASK; i100 = (x1 ^ y0 ^ z0) & TMASK;
      i010 = (x0 ^ y1 ^ z0) & TMASK; i110 = (x1 ^ y1 ^ z0) & TMASK;
      i001 = (x0 ^ y0 ^ z1) & TMASK; i101 = (x1 ^ y0 ^ z1) & TMASK;
      i011 = (x0 ^ y1 ^ z1) & TMASK; i111 = (x1 ^ y1 ^ z1) & TMASK;
    }
    const float2* t = (const float2*)table + (size_t)l * TSIZE;
    float2 f000 = t[i000], f100 = t[i100], f010 = t[i010], f110 = t[i110];
    float2 f001 = t[i001], f101 = t[i101], f011 = t[i011], f111 = t[i111];
    float wy0z0 = wy0 * wz0, wy1z0 = wy1 * wz0, wy0z1 = wy0 * wz1, wy1z1 = wy1 * wz1;
    float w000 = wx0 * wy0z0, w100 = wx1 * wy0z0, w010 = wx0 * wy1z0, w110 = wx1 * wy1z0;
    float w001 = wx0 * wy0z1, w101 = wx1 * wy0z1, w011 = wx0 * wy1z1, w111 = wx1 * wy1z1;
    h[3 + 2 * l] = w000 * f000.x + w100 * f100.x + w010 * f010.x + w110 * f110.x
                 + w001 * f001.x + w101 * f101.x + w011 * f011.x + w111 * f111.x;
    h[4 + 2 * l] = w000 * f000.y + w100 * f100.y + w010 * f010.y + w110 * f110.y
                 + w001 * f001.y + w101 * f101.y + w011 * f011.y + w111 * f111.y;
  }
  float h1[64];
  #pragma unroll
  for (int j = 0; j < 64; ++j) {
    float acc = b1[j];
    #pragma unroll
    for (int i = 0; i < 35; ++i) acc = fmaf(h[i], W1[i * 64 + j], acc);
    h1[j] = fmaxf(acc, 0.0f);
  }
  float h2[64];
  #pragma unroll
  for (int j = 0; j < 64; ++j) {
    float acc = b2[j];
    #pragma unroll
    for (int i = 0; i < 64; ++i) acc = fmaf(h1[i], W2[i * 64 + j], acc);
    h2[j] = fmaxf(acc, 0.0f);
  }
  float o = b3[0];
  #pragma unroll
  for (int i = 0; i < 64; ++i) o = fmaf(h2[i], W3[i], o);
  float v = o + 1.0f;
  out[gid] = fmaxf(v, 0.0f) + log1pf(expf(-fabsf(v)));
}

extern "C" void kernel_launch(void* const* d_in, const int* in_sizes, int n_in,
                              void* d_out, int out_size, void* d_ws, size_t ws_size,
                              hipStream_t stream) {
  const float* dirs  = (const float*)d_in[0];
  const float* table = (const float*)d_in[1];
  const float* W1 = (const float*)d_in[2];
  const float* b1 = (const float*)d_in[3];
  const float* W2 = (const float*)d_in[4];
  const float* b2 = (const float*)d_in[5];
  const float* W3 = (const float*)d_in[6];
  const float* b3 = (const float*)d_in[7];
  float* out = (float*)d_out;
  int n = in_sizes[0] / 3;

  LevelParams lp;
  double pls = std::exp(std::log(2048.0 / 16.0) / 15.0);
  unsigned dm = 0;
  for (int l = 0; l < NL; ++l) {
    double scale = 16.0 * std::pow(pls, (double)l) - 1.0;
    lp.scale[l] = (float)scale;
    long long res = (long long)std::ceil(scale) + 1;
    lp.res[l] = (unsigned)res;
    if (res * res * res <= (long long)TSIZE) dm |= (1u << l);
  }
  lp.dense_mask = dm;

  size_t feat_bytes = (size_t)n * NL * 4;  // 128 MiB at n=2M
  if (ws_size >= feat_bytes) {
    unsigned* feats = (unsigned*)d_ws;
    int chunks = (n + 255) / 256;
    hipLaunchKernelGGL(encode_k5, dim3(8 * chunks), dim3(256), 0, stream,
                       dirs, table, feats, n, lp);
    int mlp_blocks = (n + RPB - 1) / RPB;
    hipLaunchKernelGGL(mlp_mfma3, dim3(mlp_blocks), dim3(256), 0, stream,
                       dirs, feats, W1, b1, W2, b2, W3, b3, out, n);
  } else {
    int blocks = (n + 255) / 256;
    hipLaunchKernelGGL(sdf_fused, dim3(blocks), dim3(256), 0, stream,
                       dirs, table, W1, b1, W2, b2, W3, b3, out, n, lp);
  }
}